// Round 1
// baseline (1323.749 us; speedup 1.0000x reference)
//
#include <hip/hip_runtime.h>
#include <hip/hip_bf16.h>
#include <math.h>

#define DIM 2048
#define HEADS 16
#define DH 128
#define ATTN_INNER 2048
#define FF_INNER 8192
#define FUSED_N 18688
#define QKV_N 2304          // 2048 q + 128 k + 128 v
#define BATCH 2
#define SEQ 2048
#define ROWS (BATCH*SEQ)    // 4096

typedef __attribute__((ext_vector_type(8))) __bf16 bf16x8;
typedef __attribute__((ext_vector_type(4))) float f32x4;

typedef __attribute__((address_space(1))) void* as1_void;
typedef __attribute__((address_space(3))) void* as3_void;

__device__ __forceinline__ void async16(const void* g, void* l) {
  __builtin_amdgcn_global_load_lds((as1_void)const_cast<void*>(g), (as3_void)l, 16, 0, 0);
}

// ---------------- LayerNorm: fp32 [rows][2048] -> bf16 ----------------
__global__ __launch_bounds__(256) void ln_kernel(const float* __restrict__ x,
                                                 const float* __restrict__ gamma,
                                                 const float* __restrict__ beta,
                                                 __hip_bfloat16* __restrict__ hb) {
  const int row = blockIdx.x;
  const int t = threadIdx.x;
  const float4* x4 = (const float4*)(x + (size_t)row * DIM);
  float4 a = x4[t];
  float4 c = x4[t + 256];
  float s  = a.x + a.y + a.z + a.w + c.x + c.y + c.z + c.w;
  float ss = a.x*a.x + a.y*a.y + a.z*a.z + a.w*a.w +
             c.x*c.x + c.y*c.y + c.z*c.z + c.w*c.w;
  for (int off = 32; off > 0; off >>= 1) {
    s  += __shfl_down(s, off);
    ss += __shfl_down(ss, off);
  }
  __shared__ float red[8];
  int wv = t >> 6, lane = t & 63;
  if (lane == 0) { red[wv] = s; red[wv + 4] = ss; }
  __syncthreads();
  s  = red[0] + red[1] + red[2] + red[3];
  ss = red[4] + red[5] + red[6] + red[7];
  float mu  = s * (1.0f / DIM);
  float var = ss * (1.0f / DIM) - mu * mu;
  float rs  = rsqrtf(var + 1e-5f);
  __hip_bfloat16* o = hb + (size_t)row * DIM;
  float v0[4] = {a.x, a.y, a.z, a.w};
  float v1[4] = {c.x, c.y, c.z, c.w};
#pragma unroll
  for (int i = 0; i < 4; i++) {
    int c0 = t * 4 + i;
    int c1 = 1024 + t * 4 + i;
    o[c0] = __float2bfloat16((v0[i] - mu) * rs * gamma[c0] + beta[c0]);
    o[c1] = __float2bfloat16((v1[i] - mu) * rs * gamma[c1] + beta[c1]);
  }
}

// ------------- transpose + fp32->bf16: src [R][C] -> dst [C][R] -------------
__global__ __launch_bounds__(256) void tcvt_kernel(const float* __restrict__ src,
                                                   __hip_bfloat16* __restrict__ dst,
                                                   int R, int C) {
  __shared__ float tile[64][65];
  const int cb = blockIdx.x * 64, rb = blockIdx.y * 64;
  const int t = threadIdx.x;
  const int tc = t & 63, tr = t >> 6;   // 4 rows per iter
#pragma unroll
  for (int i = 0; i < 16; i++) {
    int r = tr + i * 4;
    tile[r][tc] = src[(size_t)(rb + r) * C + cb + tc];
  }
  __syncthreads();
#pragma unroll
  for (int i = 0; i < 16; i++) {
    int c = tr + i * 4;
    dst[(size_t)(cb + c) * R + rb + tc] = __float2bfloat16(tile[tc][c]);
  }
}

// ------------- transpose bf16: src [R][C] (ld) -> dst [C][R] (ldd) -------------
__global__ __launch_bounds__(256) void tbf16_kernel(const __hip_bfloat16* __restrict__ src, int lds_,
                                                    __hip_bfloat16* __restrict__ dst, int ldd,
                                                    int R, int C) {
  __shared__ __hip_bfloat16 tile[64][65];
  const int cb = blockIdx.x * 64, rb = blockIdx.y * 64;
  const int t = threadIdx.x;
  const int tc = t & 63, tr = t >> 6;
#pragma unroll
  for (int i = 0; i < 16; i++) {
    int r = tr + i * 4;
    tile[r][tc] = src[(size_t)(rb + r) * lds_ + cb + tc];
  }
  __syncthreads();
#pragma unroll
  for (int i = 0; i < 16; i++) {
    int c = tr + i * 4;
    dst[(size_t)(cb + c) * ldd + rb + tc] = tile[tc][c];
  }
}

// ---------------- RoPE in-place on qkv bf16 [4096][2304] ----------------
// u in [0,16): q head u (cols u*128 .. +128). u==16: k (cols 2048..2176).
__global__ __launch_bounds__(256) void rope_kernel(__hip_bfloat16* __restrict__ qkv) {
  const size_t tid = (size_t)blockIdx.x * 256 + threadIdx.x;  // ROWS*17*64 total
  const int d = tid & 63;
  const int u = (tid >> 6) % 17;
  const int row = tid / (17 * 64);
  const int n = row & (SEQ - 1);
  size_t base = (size_t)row * QKV_N + (u < 16 ? u * DH : ATTN_INNER);
  float inv = powf(10000.0f, -(float)d * (1.0f / 64.0f));
  float th = (float)n * inv;
  float cs = cosf(th), sn = sinf(th);
  float a = __bfloat162float(qkv[base + d]);
  float b = __bfloat162float(qkv[base + d + 64]);
  qkv[base + d]      = __float2bfloat16(a * cs - b * sn);
  qkv[base + d + 64] = __float2bfloat16(b * cs + a * sn);
}

// ---------------- BT-GEMM: C[M][N] = A[M][K] * Bt[N][K]^T ----------------
// EPI: 0 = store bf16; 1 = read bf16 C (x_ff), store silu(acc)*x_ff bf16;
//      2 = store fp32; 3 = fp32 C += acc
template<int EPI>
__global__ __launch_bounds__(256) void gemm_bt(const __hip_bfloat16* __restrict__ A, int lda,
                                               const __hip_bfloat16* __restrict__ Bt, int ldb,
                                               void* __restrict__ Cptr, int ldc, int K) {
  __shared__ __hip_bfloat16 As[128 * 32];
  __shared__ __hip_bfloat16 Bs[128 * 32];
  const int tid = threadIdx.x;
  const int wv = tid >> 6, lane = tid & 63;
  const int quad = lane >> 4, l15 = lane & 15;
  const int m0 = blockIdx.y * 128, n0 = blockIdx.x * 128;
  const int wm = (wv >> 1) * 64, wn = (wv & 1) * 64;

  f32x4 acc[4][4];
#pragma unroll
  for (int i = 0; i < 4; i++)
#pragma unroll
    for (int j = 0; j < 4; j++) acc[i][j] = (f32x4){0.f, 0.f, 0.f, 0.f};

  for (int k0 = 0; k0 < K; k0 += 32) {
#pragma unroll
    for (int j = 0; j < 2; j++) {
      int q = wv * 2 + j;
      int e = q * 512 + lane * 8;
      int row = e >> 5, col = e & 31;
      async16(A  + (size_t)(m0 + row) * lda + k0 + col, As + q * 512);
      async16(Bt + (size_t)(n0 + row) * ldb + k0 + col, Bs + q * 512);
    }
    __syncthreads();
    bf16x8 af[4], bfr[4];
#pragma unroll
    for (int i = 0; i < 4; i++)
      af[i] = *(const bf16x8*)(As + (wm + i * 16 + l15) * 32 + quad * 8);
#pragma unroll
    for (int j = 0; j < 4; j++)
      bfr[j] = *(const bf16x8*)(Bs + (wn + j * 16 + l15) * 32 + quad * 8);
#pragma unroll
    for (int i = 0; i < 4; i++)
#pragma unroll
      for (int j = 0; j < 4; j++)
        acc[i][j] = __builtin_amdgcn_mfma_f32_16x16x32_bf16(af[i], bfr[j], acc[i][j], 0, 0, 0);
    __syncthreads();
  }

  if constexpr (EPI == 0 || EPI == 1) {
    __hip_bfloat16* C = (__hip_bfloat16*)Cptr;
#pragma unroll
    for (int i = 0; i < 4; i++) {
      int rowb = m0 + wm + i * 16 + quad * 4;
#pragma unroll
      for (int j = 0; j < 4; j++) {
        int col = n0 + wn + j * 16 + l15;
#pragma unroll
        for (int r = 0; r < 4; r++) {
          float v = acc[i][j][r];
          size_t idx = (size_t)(rowb + r) * ldc + col;
          if constexpr (EPI == 1) {
            float xf = __bfloat162float(C[idx]);
            v = v / (1.0f + expf(-v)) * xf;   // silu(gate) * x_ff
          }
          C[idx] = __float2bfloat16(v);
        }
      }
    }
  } else {
    float* C = (float*)Cptr;
#pragma unroll
    for (int i = 0; i < 4; i++) {
      int rowb = m0 + wm + i * 16 + quad * 4;
#pragma unroll
      for (int j = 0; j < 4; j++) {
        int col = n0 + wn + j * 16 + l15;
#pragma unroll
        for (int r = 0; r < 4; r++) {
          size_t idx = (size_t)(rowb + r) * ldc + col;
          if constexpr (EPI == 3) C[idx] += acc[i][j][r];
          else                    C[idx]  = acc[i][j][r];
        }
      }
    }
  }
}

// ---------------- Flash attention (multi-query, causal) ----------------
// Q-tile 128, KV-tile 64. Waves 4x1 over rows: wave w owns q-rows [w*32, w*32+32).
__global__ __launch_bounds__(256) void flash_kernel(const __hip_bfloat16* __restrict__ qkv,
                                                    const __hip_bfloat16* __restrict__ vt,
                                                    __hip_bfloat16* __restrict__ aob) {
  __shared__ __hip_bfloat16 Qs[128 * 128];
  __shared__ __hip_bfloat16 Ks[64 * 128];
  __shared__ __hip_bfloat16 Vts[128 * 64];
  __shared__ __hip_bfloat16 Ps[128 * 64];

  const int blk = blockIdx.x;           // qi*32 + bh
  const int bh = blk & 31;
  const int qi = blk >> 5;
  const int qt = (qi & 1) ? (qi >> 1) : (15 - (qi >> 1));  // heavy/light interleave
  const int bat = bh >> 4, h = bh & 15;

  const int tid = threadIdx.x;
  const int wv = tid >> 6, lane = tid & 63;
  const int quad = lane >> 4, l15 = lane & 15;
  const float scale = 0.08838834764831845f;   // 1/sqrt(128)

  // stage Q tile [128 q][128 d]
#pragma unroll
  for (int j = 0; j < 8; j++) {
    int is = wv * 8 + j;
    int e = is * 512 + lane * 8;
    int r = e >> 7, c = e & 127;
    async16(qkv + (size_t)(bat * SEQ + qt * 128 + r) * QKV_N + h * DH + c, Qs + is * 512);
  }

  f32x4 oacc[2][8];
#pragma unroll
  for (int i = 0; i < 2; i++)
#pragma unroll
    for (int j = 0; j < 8; j++) oacc[i][j] = (f32x4){0.f, 0.f, 0.f, 0.f};
  float mrow[2][4], lrow[2][4];
#pragma unroll
  for (int i = 0; i < 2; i++)
#pragma unroll
    for (int r = 0; r < 4; r++) { mrow[i][r] = -INFINITY; lrow[i][r] = 0.f; }

  const int jt_max = 2 * qt + 1;
  for (int jt = 0; jt <= jt_max; jt++) {
    __syncthreads();   // prev PV done before overwriting K/V tiles
#pragma unroll
    for (int j = 0; j < 4; j++) {
      int is = wv * 4 + j;
      int e = is * 512 + lane * 8;
      { int r = e >> 7, c = e & 127;    // Ks [64 j][128 d]
        async16(qkv + (size_t)(bat * SEQ + jt * 64 + r) * QKV_N + ATTN_INNER + c, Ks + is * 512); }
      { int d = e >> 6, jc = e & 63;    // Vts [128 d][64 j]
        async16(vt + (size_t)d * ROWS + bat * SEQ + jt * 64 + jc, Vts + is * 512); }
    }
    __syncthreads();   // staging complete (vmcnt drained by barrier)

    // S = Q K^T : rows wv*32..+32, cols 0..64
    f32x4 sacc[2][4];
#pragma unroll
    for (int i = 0; i < 2; i++)
#pragma unroll
      for (int j = 0; j < 4; j++) sacc[i][j] = (f32x4){0.f, 0.f, 0.f, 0.f};
#pragma unroll
    for (int kq = 0; kq < 4; kq++) {
      bf16x8 qa[2], kb[4];
#pragma unroll
      for (int i = 0; i < 2; i++)
        qa[i] = *(const bf16x8*)(Qs + (wv * 32 + i * 16 + l15) * 128 + kq * 32 + quad * 8);
#pragma unroll
      for (int j = 0; j < 4; j++)
        kb[j] = *(const bf16x8*)(Ks + (j * 16 + l15) * 128 + kq * 32 + quad * 8);
#pragma unroll
      for (int i = 0; i < 2; i++)
#pragma unroll
        for (int j = 0; j < 4; j++)
          sacc[i][j] = __builtin_amdgcn_mfma_f32_16x16x32_bf16(qa[i], kb[j], sacc[i][j], 0, 0, 0);
    }

    // scale + causal mask + online softmax
#pragma unroll
    for (int i = 0; i < 2; i++) {
#pragma unroll
      for (int r = 0; r < 4; r++) {
        int row_g = qt * 128 + wv * 32 + i * 16 + quad * 4 + r;
        float mt = -INFINITY;
#pragma unroll
        for (int j = 0; j < 4; j++) {
          int col_g = jt * 64 + j * 16 + l15;
          float sv = sacc[i][j][r] * scale;
          if (col_g > row_g) sv = -INFINITY;
          sacc[i][j][r] = sv;
          mt = fmaxf(mt, sv);
        }
#pragma unroll
        for (int off = 1; off < 16; off <<= 1) mt = fmaxf(mt, __shfl_xor(mt, off));
        float mn = fmaxf(mrow[i][r], mt);
        float al = expf(mrow[i][r] - mn);
        float rs = 0.f;
#pragma unroll
        for (int j = 0; j < 4; j++) {
          float p = expf(sacc[i][j][r] - mn);
          sacc[i][j][r] = p;
          rs += p;
        }
#pragma unroll
        for (int off = 1; off < 16; off <<= 1) rs += __shfl_xor(rs, off);
        lrow[i][r] = lrow[i][r] * al + rs;
        mrow[i][r] = mn;
        // rescale O rows
#pragma unroll
        for (int i2 = 0; i2 < 8; i2++) oacc[i][i2][r] *= al;
      }
    }

    // write P to LDS (C-layout -> A-layout round trip)
#pragma unroll
    for (int i = 0; i < 2; i++)
#pragma unroll
      for (int j = 0; j < 4; j++)
#pragma unroll
        for (int r = 0; r < 4; r++)
          Ps[(wv * 32 + i * 16 + quad * 4 + r) * 64 + j * 16 + l15] =
              __float2bfloat16(sacc[i][j][r]);
    __syncthreads();

    // O += P V : K-dim = 64 kv, N = 128 d
#pragma unroll
    for (int kp = 0; kp < 2; kp++) {
      bf16x8 pa[2], vb[8];
#pragma unroll
      for (int i = 0; i < 2; i++)
        pa[i] = *(const bf16x8*)(Ps + (wv * 32 + i * 16 + l15) * 64 + kp * 32 + quad * 8);
#pragma unroll
      for (int i2 = 0; i2 < 8; i2++)
        vb[i2] = *(const bf16x8*)(Vts + (i2 * 16 + l15) * 64 + kp * 32 + quad * 8);
#pragma unroll
      for (int i = 0; i < 2; i++)
#pragma unroll
        for (int i2 = 0; i2 < 8; i2++)
          oacc[i][i2] = __builtin_amdgcn_mfma_f32_16x16x32_bf16(pa[i], vb[i2], oacc[i][i2], 0, 0, 0);
    }
  }

  // normalize + write out [b][n][h*128+d] bf16
#pragma unroll
  for (int i = 0; i < 2; i++)
#pragma unroll
    for (int r = 0; r < 4; r++) {
      float inv = 1.0f / lrow[i][r];
      int row_g = bat * SEQ + qt * 128 + wv * 32 + i * 16 + quad * 4 + r;
#pragma unroll
      for (int i2 = 0; i2 < 8; i2++)
        aob[(size_t)row_g * ATTN_INNER + h * DH + i2 * 16 + l15] =
            __float2bfloat16(oacc[i][i2][r] * inv);
    }
}

// ---------------- host ----------------
extern "C" void kernel_launch(void* const* d_in, const int* in_sizes, int n_in,
                              void* d_out, int out_size, void* d_ws, size_t ws_size,
                              hipStream_t stream) {
  const float* x       = (const float*)d_in[0];
  const float* gamma   = (const float*)d_in[1];
  const float* beta    = (const float*)d_in[2];
  const float* w_fused = (const float*)d_in[3];
  const float* w_attn  = (const float*)d_in[4];
  const float* w_ff    = (const float*)d_in[5];
  float* out = (float*)d_out;
  char* ws = (char*)d_ws;

  size_t off = 0;
  auto alloc = [&](size_t bytes) {
    size_t o = off;
    off += (bytes + 255) & ~(size_t)255;
    return o;
  };
  __hip_bfloat16* hb   = (__hip_bfloat16*)(ws + alloc((size_t)ROWS * DIM * 2));
  __hip_bfloat16* wfbt = (__hip_bfloat16*)(ws + alloc((size_t)FUSED_N * DIM * 2));
  __hip_bfloat16* qkvb = (__hip_bfloat16*)(ws + alloc((size_t)ROWS * QKV_N * 2));
  __hip_bfloat16* gb   = (__hip_bfloat16*)(ws + alloc((size_t)ROWS * FF_INNER * 2));
  __hip_bfloat16* wat  = (__hip_bfloat16*)(ws + alloc((size_t)DIM * ATTN_INNER * 2));
  __hip_bfloat16* wfot = (__hip_bfloat16*)(ws + alloc((size_t)DIM * FF_INNER * 2));
  __hip_bfloat16* vt   = (__hip_bfloat16*)(ws + alloc((size_t)DH * ROWS * 2));
  __hip_bfloat16* aob  = (__hip_bfloat16*)(ws + alloc((size_t)ROWS * ATTN_INNER * 2));

  // 1. LayerNorm -> bf16
  ln_kernel<<<ROWS, 256, 0, stream>>>(x, gamma, beta, hb);

  // 2. weight transpose+convert (dst [N][K])
  tcvt_kernel<<<dim3(FUSED_N / 64, DIM / 64), 256, 0, stream>>>(w_fused, wfbt, DIM, FUSED_N);
  tcvt_kernel<<<dim3(DIM / 64, ATTN_INNER / 64), 256, 0, stream>>>(w_attn, wat, ATTN_INNER, DIM);
  tcvt_kernel<<<dim3(DIM / 64, FF_INNER / 64), 256, 0, stream>>>(w_ff, wfot, FF_INNER, DIM);

  // 3. qkv projection: [4096][2304]
  gemm_bt<0><<<dim3(QKV_N / 128, ROWS / 128), 256, 0, stream>>>(hb, DIM, wfbt, DIM, qkvb, QKV_N, DIM);

  // 4. RoPE on q (16 heads) and k, in place
  rope_kernel<<<(ROWS * 17 * 64) / 256, 256, 0, stream>>>(qkvb);

  // 5. v transpose: [4096][128] (ld 2304) -> vt [128][4096]
  tbf16_kernel<<<dim3(DH / 64, ROWS / 64), 256, 0, stream>>>(qkvb + ATTN_INNER + DH, QKV_N, vt, ROWS, ROWS, DH);

  // 6. flash attention -> aob [4096][2048]
  flash_kernel<<<512, 256, 0, stream>>>(qkvb, vt, aob);

  // 7. x_ff projection -> gb
  gemm_bt<0><<<dim3(FF_INNER / 128, ROWS / 128), 256, 0, stream>>>(
      hb, DIM, wfbt + (size_t)QKV_N * DIM, DIM, gb, FF_INNER, DIM);
  // 8. gate projection, fused silu(gate)*x_ff -> gb
  gemm_bt<1><<<dim3(FF_INNER / 128, ROWS / 128), 256, 0, stream>>>(
      hb, DIM, wfbt + (size_t)(QKV_N + FF_INNER) * DIM, DIM, gb, FF_INNER, DIM);

  // 9. out = aob @ w_attn_out (fp32 store)
  gemm_bt<2><<<dim3(DIM / 128, ROWS / 128), 256, 0, stream>>>(aob, ATTN_INNER, wat, ATTN_INNER, out, DIM, ATTN_INNER);
  // 10. out += gb @ w_ff_out
  gemm_bt<3><<<dim3(DIM / 128, ROWS / 128), 256, 0, stream>>>(gb, FF_INNER, wfot, FF_INNER, out, DIM, FF_INNER);

  (void)in_sizes; (void)n_in; (void)out_size; (void)ws_size;
}

// Round 2
// 1149.742 us; speedup vs baseline: 1.1513x; 1.1513x over previous
//
#include <hip/hip_runtime.h>
#include <hip/hip_bf16.h>
#include <math.h>

#define DIM 2048
#define HEADS 16
#define DH 128
#define ATTN_INNER 2048
#define FF_INNER 8192
#define FUSED_N 18688
#define QKV_N 2304          // 2048 q + 128 k + 128 v
#define BATCH 2
#define SEQ 2048
#define ROWS (BATCH*SEQ)    // 4096

typedef __attribute__((ext_vector_type(8))) __bf16 bf16x8;
typedef __attribute__((ext_vector_type(4))) float f32x4;

typedef __attribute__((address_space(1))) void* as1_void;
typedef __attribute__((address_space(3))) void* as3_void;

__device__ __forceinline__ void async16(const void* g, void* l) {
  __builtin_amdgcn_global_load_lds((as1_void)const_cast<void*>(g), (as3_void)l, 16, 0, 0);
}

// GROUP_M=8 swizzle: consecutive block ids sweep 8 M-tiles then advance N.
// A compact ~256-id window touches 8 A-slabs + streams B -> L2/L3 friendly.
__device__ __forceinline__ void swizzle_tile(int& tm, int& tn) {
  const int num_n = gridDim.x;
  const int pid = blockIdx.y * num_n + blockIdx.x;
  const int group = 8 * num_n;
  const int gid = pid / group;
  const int rem = pid % group;
  tm = gid * 8 + (rem % 8);
  tn = rem / 8;
}

// ---------------- LayerNorm: fp32 [rows][2048] -> bf16 ----------------
__global__ __launch_bounds__(256) void ln_kernel(const float* __restrict__ x,
                                                 const float* __restrict__ gamma,
                                                 const float* __restrict__ beta,
                                                 __hip_bfloat16* __restrict__ hb) {
  const int row = blockIdx.x;
  const int t = threadIdx.x;
  const float4* x4 = (const float4*)(x + (size_t)row * DIM);
  float4 a = x4[t];
  float4 c = x4[t + 256];
  float s  = a.x + a.y + a.z + a.w + c.x + c.y + c.z + c.w;
  float ss = a.x*a.x + a.y*a.y + a.z*a.z + a.w*a.w +
             c.x*c.x + c.y*c.y + c.z*c.z + c.w*c.w;
  for (int off = 32; off > 0; off >>= 1) {
    s  += __shfl_down(s, off);
    ss += __shfl_down(ss, off);
  }
  __shared__ float red[8];
  int wv = t >> 6, lane = t & 63;
  if (lane == 0) { red[wv] = s; red[wv + 4] = ss; }
  __syncthreads();
  s  = red[0] + red[1] + red[2] + red[3];
  ss = red[4] + red[5] + red[6] + red[7];
  float mu  = s * (1.0f / DIM);
  float var = ss * (1.0f / DIM) - mu * mu;
  float rs  = rsqrtf(var + 1e-5f);
  __hip_bfloat16* o = hb + (size_t)row * DIM;
  float v0[4] = {a.x, a.y, a.z, a.w};
  float v1[4] = {c.x, c.y, c.z, c.w};
#pragma unroll
  for (int i = 0; i < 4; i++) {
    int c0 = t * 4 + i;
    int c1 = 1024 + t * 4 + i;
    o[c0] = __float2bfloat16((v0[i] - mu) * rs * gamma[c0] + beta[c0]);
    o[c1] = __float2bfloat16((v1[i] - mu) * rs * gamma[c1] + beta[c1]);
  }
}

// ------------- transpose + fp32->bf16: src [R][C] -> dst [C][R] -------------
// float4 loads, bf16x2 stores.
__global__ __launch_bounds__(256) void tcvt_kernel(const float* __restrict__ src,
                                                   __hip_bfloat16* __restrict__ dst,
                                                   int R, int C) {
  __shared__ float tile[64][65];
  const int cb = blockIdx.x * 64, rb = blockIdx.y * 64;
  const int t = threadIdx.x;
  const int lr = t >> 4, lc4 = (t & 15) * 4;
#pragma unroll
  for (int i = 0; i < 4; i++) {
    float4 v = *(const float4*)&src[(size_t)(rb + lr + i * 16) * C + cb + lc4];
    tile[lr + i * 16][lc4 + 0] = v.x;
    tile[lr + i * 16][lc4 + 1] = v.y;
    tile[lr + i * 16][lc4 + 2] = v.z;
    tile[lr + i * 16][lc4 + 3] = v.w;
  }
  __syncthreads();
  const int tcc = t & 31, trc = t >> 5;
#pragma unroll
  for (int i = 0; i < 8; i++) {
    int c = trc + i * 8;
    __hip_bfloat162 pk;
    pk.x = __float2bfloat16(tile[2 * tcc][c]);
    pk.y = __float2bfloat16(tile[2 * tcc + 1][c]);
    *(__hip_bfloat162*)&dst[(size_t)(cb + c) * R + rb + 2 * tcc] = pk;
  }
}

// ------------- transpose bf16: src [R][C] (ld) -> dst [C][R] (ldd) -------------
__global__ __launch_bounds__(256) void tbf16_kernel(const __hip_bfloat16* __restrict__ src, int lds_,
                                                    __hip_bfloat16* __restrict__ dst, int ldd,
                                                    int R, int C) {
  __shared__ __hip_bfloat16 tile[64][65];
  const int cb = blockIdx.x * 64, rb = blockIdx.y * 64;
  const int t = threadIdx.x;
  const int tc = t & 63, tr = t >> 6;
#pragma unroll
  for (int i = 0; i < 16; i++) {
    int r = tr + i * 4;
    tile[r][tc] = src[(size_t)(rb + r) * lds_ + cb + tc];
  }
  __syncthreads();
#pragma unroll
  for (int i = 0; i < 16; i++) {
    int c = tr + i * 4;
    dst[(size_t)(cb + c) * ldd + rb + tc] = tile[tc][c];
  }
}

// ---------------- RoPE in-place on qkv bf16 [4096][2304] ----------------
__global__ __launch_bounds__(256) void rope_kernel(__hip_bfloat16* __restrict__ qkv) {
  const size_t tid = (size_t)blockIdx.x * 256 + threadIdx.x;  // ROWS*17*64 total
  const int d = tid & 63;
  const int u = (tid >> 6) % 17;
  const int row = tid / (17 * 64);
  const int n = row & (SEQ - 1);
  size_t base = (size_t)row * QKV_N + (u < 16 ? u * DH : ATTN_INNER);
  float inv = powf(10000.0f, -(float)d * (1.0f / 64.0f));
  float th = (float)n * inv;
  float cs = cosf(th), sn = sinf(th);
  float a = __bfloat162float(qkv[base + d]);
  float b = __bfloat162float(qkv[base + d + 64]);
  qkv[base + d]      = __float2bfloat16(a * cs - b * sn);
  qkv[base + d + 64] = __float2bfloat16(b * cs + a * sn);
}

// ---------------- qkv GEMM: C[4096][2304] = hb[4096][2048] * wfbt[0:2304][2048]^T
__global__ __launch_bounds__(256, 3) void gemm_qkv(const __hip_bfloat16* __restrict__ A,
                                                   const __hip_bfloat16* __restrict__ Bt,
                                                   __hip_bfloat16* __restrict__ C) {
  __shared__ __hip_bfloat16 As[2][128 * 32];
  __shared__ __hip_bfloat16 Bs[2][128 * 32];
  const int tid = threadIdx.x;
  const int wv = tid >> 6, lane = tid & 63;
  const int quad = lane >> 4, l15 = lane & 15;
  int tm, tn; swizzle_tile(tm, tn);
  const int m0 = tm * 128, n0 = tn * 128;
  const int wm = (wv >> 1) * 64, wn = (wv & 1) * 64;
  const int srow = lane >> 2, scol = (lane & 3) * 8;

  f32x4 acc[4][4] = {};
  for (int k0 = 0; k0 < DIM; k0 += 64) {
#pragma unroll
    for (int h = 0; h < 2; h++)
#pragma unroll
      for (int j = 0; j < 2; j++) {
        int q = wv * 2 + j;
        int row = q * 16 + srow;
        async16(A  + (size_t)(m0 + row) * DIM + k0 + h * 32 + scol, &As[h][q * 512]);
        async16(Bt + (size_t)(n0 + row) * DIM + k0 + h * 32 + scol, &Bs[h][q * 512]);
      }
    __syncthreads();
#pragma unroll
    for (int h = 0; h < 2; h++) {
      bf16x8 af[4], bfr[4];
#pragma unroll
      for (int i = 0; i < 4; i++)
        af[i] = *(const bf16x8*)(&As[h][(wm + i * 16 + l15) * 32 + quad * 8]);
#pragma unroll
      for (int j = 0; j < 4; j++)
        bfr[j] = *(const bf16x8*)(&Bs[h][(wn + j * 16 + l15) * 32 + quad * 8]);
#pragma unroll
      for (int i = 0; i < 4; i++)
#pragma unroll
        for (int j = 0; j < 4; j++)
          acc[i][j] = __builtin_amdgcn_mfma_f32_16x16x32_bf16(af[i], bfr[j], acc[i][j], 0, 0, 0);
    }
    __syncthreads();
  }
#pragma unroll
  for (int i = 0; i < 4; i++) {
    int rowb = m0 + wm + i * 16 + quad * 4;
#pragma unroll
    for (int j = 0; j < 4; j++) {
      int col = n0 + wn + j * 16 + l15;
#pragma unroll
      for (int r = 0; r < 4; r++)
        C[(size_t)(rowb + r) * QKV_N + col] = __float2bfloat16(acc[i][j][r]);
    }
  }
}

// ---------------- merged FF GEMM: gb[4096][8192] = silu(h@Wg^T) * (h@Wx^T)
// Block computes 128 M x 64 N of BOTH halves (Bs rows 0-63 = x_ff, 64-127 = gate).
__global__ __launch_bounds__(256, 3) void gemm_ff(const __hip_bfloat16* __restrict__ A,
                                                  const __hip_bfloat16* __restrict__ W,   // wfbt
                                                  __hip_bfloat16* __restrict__ G) {
  __shared__ __hip_bfloat16 As[2][128 * 32];
  __shared__ __hip_bfloat16 Bs[2][128 * 32];
  const int tid = threadIdx.x;
  const int wv = tid >> 6, lane = tid & 63;
  const int quad = lane >> 4, l15 = lane & 15;
  int tm, tn; swizzle_tile(tm, tn);
  const int m0 = tm * 128, n0 = tn * 64;
  const int wm = (wv >> 1) * 64, wn2 = (wv & 1) * 32;
  const int srow = lane >> 2, scol = (lane & 3) * 8;

  f32x4 ax[4][2] = {};
  f32x4 ag[4][2] = {};
  for (int k0 = 0; k0 < DIM; k0 += 64) {
#pragma unroll
    for (int h = 0; h < 2; h++)
#pragma unroll
      for (int j = 0; j < 2; j++) {
        int q = wv * 2 + j;
        int row = q * 16 + srow;
        async16(A + (size_t)(m0 + row) * DIM + k0 + h * 32 + scol, &As[h][q * 512]);
        int wr = (row < 64) ? (QKV_N + n0 + row)
                            : (QKV_N + FF_INNER + n0 + row - 64);
        async16(W + (size_t)wr * DIM + k0 + h * 32 + scol, &Bs[h][q * 512]);
      }
    __syncthreads();
#pragma unroll
    for (int h = 0; h < 2; h++) {
      bf16x8 af[4], bx[2], bg[2];
#pragma unroll
      for (int i = 0; i < 4; i++)
        af[i] = *(const bf16x8*)(&As[h][(wm + i * 16 + l15) * 32 + quad * 8]);
#pragma unroll
      for (int j = 0; j < 2; j++) {
        bx[j] = *(const bf16x8*)(&Bs[h][(wn2 + j * 16 + l15) * 32 + quad * 8]);
        bg[j] = *(const bf16x8*)(&Bs[h][(64 + wn2 + j * 16 + l15) * 32 + quad * 8]);
      }
#pragma unroll
      for (int i = 0; i < 4; i++)
#pragma unroll
        for (int j = 0; j < 2; j++) {
          ax[i][j] = __builtin_amdgcn_mfma_f32_16x16x32_bf16(af[i], bx[j], ax[i][j], 0, 0, 0);
          ag[i][j] = __builtin_amdgcn_mfma_f32_16x16x32_bf16(af[i], bg[j], ag[i][j], 0, 0, 0);
        }
    }
    __syncthreads();
  }
#pragma unroll
  for (int i = 0; i < 4; i++) {
    int rowb = m0 + wm + i * 16 + quad * 4;
#pragma unroll
    for (int j = 0; j < 2; j++) {
      int col = n0 + wn2 + j * 16 + l15;
#pragma unroll
      for (int r = 0; r < 4; r++) {
        float xv = ax[i][j][r];
        float gv = ag[i][j][r];
        float o = gv / (1.0f + expf(-gv)) * xv;
        G[(size_t)(rowb + r) * FF_INNER + col] = __float2bfloat16(o);
      }
    }
  }
}

// ---------------- merged output GEMM: out = aob@wat^T + gb@wfot^T (fp32 store)
__global__ __launch_bounds__(256, 3) void gemm_out(const __hip_bfloat16* __restrict__ A0,
                                                   const __hip_bfloat16* __restrict__ B0,
                                                   const __hip_bfloat16* __restrict__ A1,
                                                   const __hip_bfloat16* __restrict__ B1,
                                                   float* __restrict__ C) {
  __shared__ __hip_bfloat16 As[2][128 * 32];
  __shared__ __hip_bfloat16 Bs[2][128 * 32];
  const int tid = threadIdx.x;
  const int wv = tid >> 6, lane = tid & 63;
  const int quad = lane >> 4, l15 = lane & 15;
  int tm, tn; swizzle_tile(tm, tn);
  const int m0 = tm * 128, n0 = tn * 128;
  const int wm = (wv >> 1) * 64, wn = (wv & 1) * 64;
  const int srow = lane >> 2, scol = (lane & 3) * 8;

  f32x4 acc[4][4] = {};
  for (int p = 0; p < 2; p++) {
    const __hip_bfloat16* A = p ? A1 : A0;
    const __hip_bfloat16* B = p ? B1 : B0;
    const int K = p ? FF_INNER : ATTN_INNER;   // lda == ldb == K for both phases
    for (int k0 = 0; k0 < K; k0 += 64) {
#pragma unroll
      for (int h = 0; h < 2; h++)
#pragma unroll
        for (int j = 0; j < 2; j++) {
          int q = wv * 2 + j;
          int row = q * 16 + srow;
          async16(A + (size_t)(m0 + row) * K + k0 + h * 32 + scol, &As[h][q * 512]);
          async16(B + (size_t)(n0 + row) * K + k0 + h * 32 + scol, &Bs[h][q * 512]);
        }
      __syncthreads();
#pragma unroll
      for (int h = 0; h < 2; h++) {
        bf16x8 af[4], bfr[4];
#pragma unroll
        for (int i = 0; i < 4; i++)
          af[i] = *(const bf16x8*)(&As[h][(wm + i * 16 + l15) * 32 + quad * 8]);
#pragma unroll
        for (int j = 0; j < 4; j++)
          bfr[j] = *(const bf16x8*)(&Bs[h][(wn + j * 16 + l15) * 32 + quad * 8]);
#pragma unroll
        for (int i = 0; i < 4; i++)
#pragma unroll
          for (int j = 0; j < 4; j++)
            acc[i][j] = __builtin_amdgcn_mfma_f32_16x16x32_bf16(af[i], bfr[j], acc[i][j], 0, 0, 0);
      }
      __syncthreads();
    }
  }
#pragma unroll
  for (int i = 0; i < 4; i++) {
    int rowb = m0 + wm + i * 16 + quad * 4;
#pragma unroll
    for (int j = 0; j < 4; j++) {
      int col = n0 + wn + j * 16 + l15;
#pragma unroll
      for (int r = 0; r < 4; r++)
        C[(size_t)(rowb + r) * DIM + col] = acc[i][j][r];
    }
  }
}

// ---------------- Flash attention (multi-query, causal) ----------------
__global__ __launch_bounds__(256) void flash_kernel(const __hip_bfloat16* __restrict__ qkv,
                                                    const __hip_bfloat16* __restrict__ vt,
                                                    __hip_bfloat16* __restrict__ aob) {
  __shared__ __hip_bfloat16 Qs[128 * 128];
  __shared__ __hip_bfloat16 Ks[64 * 128];
  __shared__ __hip_bfloat16 Vts[128 * 64];
  __shared__ __hip_bfloat16 Ps[128 * 64];

  const int blk = blockIdx.x;           // qi*32 + bh
  const int bh = blk & 31;
  const int qi = blk >> 5;
  const int qt = (qi & 1) ? (qi >> 1) : (15 - (qi >> 1));  // heavy/light interleave
  const int bat = bh >> 4, h = bh & 15;

  const int tid = threadIdx.x;
  const int wv = tid >> 6, lane = tid & 63;
  const int quad = lane >> 4, l15 = lane & 15;
  const float scale = 0.08838834764831845f;   // 1/sqrt(128)

#pragma unroll
  for (int j = 0; j < 8; j++) {
    int is = wv * 8 + j;
    int e = is * 512 + lane * 8;
    int r = e >> 7, c = e & 127;
    async16(qkv + (size_t)(bat * SEQ + qt * 128 + r) * QKV_N + h * DH + c, Qs + is * 512);
  }

  f32x4 oacc[2][8];
#pragma unroll
  for (int i = 0; i < 2; i++)
#pragma unroll
    for (int j = 0; j < 8; j++) oacc[i][j] = (f32x4){0.f, 0.f, 0.f, 0.f};
  float mrow[2][4], lrow[2][4];
#pragma unroll
  for (int i = 0; i < 2; i++)
#pragma unroll
    for (int r = 0; r < 4; r++) { mrow[i][r] = -INFINITY; lrow[i][r] = 0.f; }

  const int jt_max = 2 * qt + 1;
  for (int jt = 0; jt <= jt_max; jt++) {
    __syncthreads();
#pragma unroll
    for (int j = 0; j < 4; j++) {
      int is = wv * 4 + j;
      int e = is * 512 + lane * 8;
      { int r = e >> 7, c = e & 127;
        async16(qkv + (size_t)(bat * SEQ + jt * 64 + r) * QKV_N + ATTN_INNER + c, Ks + is * 512); }
      { int d = e >> 6, jc = e & 63;
        async16(vt + (size_t)d * ROWS + bat * SEQ + jt * 64 + jc, Vts + is * 512); }
    }
    __syncthreads();

    f32x4 sacc[2][4];
#pragma unroll
    for (int i = 0; i < 2; i++)
#pragma unroll
      for (int j = 0; j < 4; j++) sacc[i][j] = (f32x4){0.f, 0.f, 0.f, 0.f};
#pragma unroll
    for (int kq = 0; kq < 4; kq++) {
      bf16x8 qa[2], kb[4];
#pragma unroll
      for (int i = 0; i < 2; i++)
        qa[i] = *(const bf16x8*)(Qs + (wv * 32 + i * 16 + l15) * 128 + kq * 32 + quad * 8);
#pragma unroll
      for (int j = 0; j < 4; j++)
        kb[j] = *(const bf16x8*)(Ks + (j * 16 + l15) * 128 + kq * 32 + quad * 8);
#pragma unroll
      for (int i = 0; i < 2; i++)
#pragma unroll
        for (int j = 0; j < 4; j++)
          sacc[i][j] = __builtin_amdgcn_mfma_f32_16x16x32_bf16(qa[i], kb[j], sacc[i][j], 0, 0, 0);
    }

#pragma unroll
    for (int i = 0; i < 2; i++) {
#pragma unroll
      for (int r = 0; r < 4; r++) {
        int row_g = qt * 128 + wv * 32 + i * 16 + quad * 4 + r;
        float mt = -INFINITY;
#pragma unroll
        for (int j = 0; j < 4; j++) {
          int col_g = jt * 64 + j * 16 + l15;
          float sv = sacc[i][j][r] * scale;
          if (col_g > row_g) sv = -INFINITY;
          sacc[i][j][r] = sv;
          mt = fmaxf(mt, sv);
        }
#pragma unroll
        for (int off = 1; off < 16; off <<= 1) mt = fmaxf(mt, __shfl_xor(mt, off));
        float mn = fmaxf(mrow[i][r], mt);
        float al = expf(mrow[i][r] - mn);
        float rs = 0.f;
#pragma unroll
        for (int j = 0; j < 4; j++) {
          float p = expf(sacc[i][j][r] - mn);
          sacc[i][j][r] = p;
          rs += p;
        }
#pragma unroll
        for (int off = 1; off < 16; off <<= 1) rs += __shfl_xor(rs, off);
        lrow[i][r] = lrow[i][r] * al + rs;
        mrow[i][r] = mn;
#pragma unroll
        for (int i2 = 0; i2 < 8; i2++) oacc[i][i2][r] *= al;
      }
    }

#pragma unroll
    for (int i = 0; i < 2; i++)
#pragma unroll
      for (int j = 0; j < 4; j++)
#pragma unroll
        for (int r = 0; r < 4; r++)
          Ps[(wv * 32 + i * 16 + quad * 4 + r) * 64 + j * 16 + l15] =
              __float2bfloat16(sacc[i][j][r]);
    __syncthreads();

#pragma unroll
    for (int kp = 0; kp < 2; kp++) {
      bf16x8 pa[2], vb[8];
#pragma unroll
      for (int i = 0; i < 2; i++)
        pa[i] = *(const bf16x8*)(Ps + (wv * 32 + i * 16 + l15) * 64 + kp * 32 + quad * 8);
#pragma unroll
      for (int i2 = 0; i2 < 8; i2++)
        vb[i2] = *(const bf16x8*)(Vts + (i2 * 16 + l15) * 64 + kp * 32 + quad * 8);
#pragma unroll
      for (int i = 0; i < 2; i++)
#pragma unroll
        for (int i2 = 0; i2 < 8; i2++)
          oacc[i][i2] = __builtin_amdgcn_mfma_f32_16x16x32_bf16(pa[i], vb[i2], oacc[i][i2], 0, 0, 0);
    }
  }

#pragma unroll
  for (int i = 0; i < 2; i++)
#pragma unroll
    for (int r = 0; r < 4; r++) {
      float inv = 1.0f / lrow[i][r];
      int row_g = bat * SEQ + qt * 128 + wv * 32 + i * 16 + quad * 4 + r;
#pragma unroll
      for (int i2 = 0; i2 < 8; i2++)
        aob[(size_t)row_g * ATTN_INNER + h * DH + i2 * 16 + l15] =
            __float2bfloat16(oacc[i][i2][r] * inv);
    }
}

// ---------------- host ----------------
extern "C" void kernel_launch(void* const* d_in, const int* in_sizes, int n_in,
                              void* d_out, int out_size, void* d_ws, size_t ws_size,
                              hipStream_t stream) {
  const float* x       = (const float*)d_in[0];
  const float* gamma   = (const float*)d_in[1];
  const float* beta    = (const float*)d_in[2];
  const float* w_fused = (const float*)d_in[3];
  const float* w_attn  = (const float*)d_in[4];
  const float* w_ff    = (const float*)d_in[5];
  float* out = (float*)d_out;
  char* ws = (char*)d_ws;

  size_t off = 0;
  auto alloc = [&](size_t bytes) {
    size_t o = off;
    off += (bytes + 255) & ~(size_t)255;
    return o;
  };
  __hip_bfloat16* hb   = (__hip_bfloat16*)(ws + alloc((size_t)ROWS * DIM * 2));
  __hip_bfloat16* wfbt = (__hip_bfloat16*)(ws + alloc((size_t)FUSED_N * DIM * 2));
  __hip_bfloat16* qkvb = (__hip_bfloat16*)(ws + alloc((size_t)ROWS * QKV_N * 2));
  __hip_bfloat16* gb   = (__hip_bfloat16*)(ws + alloc((size_t)ROWS * FF_INNER * 2));
  __hip_bfloat16* wat  = (__hip_bfloat16*)(ws + alloc((size_t)DIM * ATTN_INNER * 2));
  __hip_bfloat16* wfot = (__hip_bfloat16*)(ws + alloc((size_t)DIM * FF_INNER * 2));
  __hip_bfloat16* vt   = (__hip_bfloat16*)(ws + alloc((size_t)DH * ROWS * 2));
  __hip_bfloat16* aob  = (__hip_bfloat16*)(ws + alloc((size_t)ROWS * ATTN_INNER * 2));

  ln_kernel<<<ROWS, 256, 0, stream>>>(x, gamma, beta, hb);

  tcvt_kernel<<<dim3(FUSED_N / 64, DIM / 64), 256, 0, stream>>>(w_fused, wfbt, DIM, FUSED_N);
  tcvt_kernel<<<dim3(DIM / 64, ATTN_INNER / 64), 256, 0, stream>>>(w_attn, wat, ATTN_INNER, DIM);
  tcvt_kernel<<<dim3(DIM / 64, FF_INNER / 64), 256, 0, stream>>>(w_ff, wfot, FF_INNER, DIM);

  gemm_qkv<<<dim3(QKV_N / 128, ROWS / 128), 256, 0, stream>>>(hb, wfbt, qkvb);

  rope_kernel<<<(ROWS * 17 * 64) / 256, 256, 0, stream>>>(qkvb);

  tbf16_kernel<<<dim3(DH / 64, ROWS / 64), 256, 0, stream>>>(qkvb + ATTN_INNER + DH, QKV_N, vt, ROWS, ROWS, DH);

  flash_kernel<<<512, 256, 0, stream>>>(qkvb, vt, aob);

  gemm_ff<<<dim3(FF_INNER / 64, ROWS / 128), 256, 0, stream>>>(hb, wfbt, gb);

  gemm_out<<<dim3(DIM / 128, ROWS / 128), 256, 0, stream>>>(aob, wat, gb, wfot, out);

  (void)in_sizes; (void)n_in; (void)out_size; (void)ws_size;
}